// Round 5
// baseline (394.806 us; speedup 1.0000x reference)
//
#include <hip/hip_runtime.h>
#include <hip/hip_bf16.h>
#include <math.h>

#define B_ 4
#define S_ 2048
#define D_ 512
#define H_ 8
#define DK_ 64

typedef __bf16 bf16x8 __attribute__((ext_vector_type(8)));
typedef float f32x16 __attribute__((ext_vector_type(16)));
typedef float f32x4 __attribute__((ext_vector_type(4)));

static __device__ __forceinline__ unsigned short f2bf(float f) {
    unsigned int u = __builtin_bit_cast(unsigned int, f);
    unsigned int r = (u + 0x7FFFu + ((u >> 16) & 1u)) >> 16;
    return (unsigned short)r;
}

// ---- x (f32) -> bf16, vectorized ----
__global__ void k_convert_x(const float* __restrict__ x, unsigned short* __restrict__ xb, int n4) {
    int i = blockIdx.x * blockDim.x + threadIdx.x;
    if (i >= n4) return;
    const float4 v = reinterpret_cast<const float4*>(x)[i];
    ushort4 o;
    o.x = f2bf(v.x); o.y = f2bf(v.y); o.z = f2bf(v.z); o.w = f2bf(v.w);
    reinterpret_cast<ushort4*>(xb)[i] = o;
}

// ---- W_Q/W_K [H][D][DK] f32 -> [H][DK][D] bf16 ----
__global__ void k_transpose_w(const float* __restrict__ wq, const float* __restrict__ wk,
                              unsigned short* __restrict__ wqT, unsigned short* __restrict__ wkT) {
    int idx = blockIdx.x * blockDim.x + threadIdx.x;
    const int n = H_ * DK_ * D_;
    const float* src = idx < n ? wq : wk;
    unsigned short* dst = idx < n ? wqT : wkT;
    int o = idx < n ? idx : idx - n;
    int d  = o % D_;
    int hk = o / D_;
    int k  = hk % DK_;
    int h  = hk / DK_;
    dst[o] = f2bf(src[(h * D_ + d) * DK_ + k]);
}

// ---- decay table tab[h][n] = gamma_h^n ----
__global__ void k_decay(float* __restrict__ tab) {
    int i = blockIdx.x * blockDim.x + threadIdx.x;
    if (i >= H_ * S_) return;
    int h = i / S_;
    int n = i % S_;
    double xv = -3.4657359027997265 - (double)h * (2.772588722239781 / 7.0);
    double g = 1.0 - exp(xv);
    tab[i] = (float)pow(g, (double)n);
}

// ---- zero output 0 (reference out == 0 exactly: GroupNorm group-size 1) ----
__global__ void k_zero(float4* __restrict__ p, int n4) {
    int i = blockIdx.x * blockDim.x + threadIdx.x;
    if (i < n4) { float4 z = {0.f, 0.f, 0.f, 0.f}; p[i] = z; }
}

// ---- projection GEMM: [B*S, D] x [D, H*DK] -> Q/K bf16 [B][H][S][DK] ----
__global__ __launch_bounds__(256) void k_proj(const unsigned short* __restrict__ xb,
                                              const unsigned short* __restrict__ wqT,
                                              const unsigned short* __restrict__ wkT,
                                              unsigned short* __restrict__ qb,
                                              unsigned short* __restrict__ kb) {
    const int lane = threadIdx.x & 63;
    const int wave = threadIdx.x >> 6;
    const int h = blockIdx.x;
    const int m0 = blockIdx.y * 128 + wave * 32;
    const unsigned short* wt = (blockIdx.z == 0) ? wqT : wkT;
    unsigned short* out = (blockIdx.z == 0) ? qb : kb;

    const int row  = lane & 31;
    const int koff = (lane >> 5) * 8;

    f32x16 acc0 = {};
    f32x16 acc1 = {};
    const unsigned short* aptr = xb + (size_t)(m0 + row) * D_ + koff;
    const unsigned short* b0   = wt + (size_t)(h * DK_ + row) * D_ + koff;
    const unsigned short* b1   = wt + (size_t)(h * DK_ + 32 + row) * D_ + koff;
    for (int kk = 0; kk < D_; kk += 16) {
        bf16x8 a  = *reinterpret_cast<const bf16x8*>(aptr + kk);
        bf16x8 v0 = *reinterpret_cast<const bf16x8*>(b0 + kk);
        bf16x8 v1 = *reinterpret_cast<const bf16x8*>(b1 + kk);
        acc0 = __builtin_amdgcn_mfma_f32_32x32x16_bf16(a, v0, acc0, 0, 0, 0);
        acc1 = __builtin_amdgcn_mfma_f32_32x32x16_bf16(a, v1, acc1, 0, 0, 0);
    }
#pragma unroll
    for (int r = 0; r < 16; ++r) {
        int rowD = (r & 3) + 8 * (r >> 2) + 4 * (lane >> 5);
        int m = m0 + rowD;
        int bidx = m >> 11, s = m & 2047;
        size_t base = (((size_t)bidx * H_ + h) * S_ + s) * DK_;
        out[base + row]      = f2bf(acc0[r]);
        out[base + 32 + row] = f2bf(acc1[r]);
    }
}

// ---- scores, row-panel streaming version (identical to round 4) ----
__global__ __launch_bounds__(256) void k_score(const unsigned short* __restrict__ qb,
                                               const unsigned short* __restrict__ kb,
                                               const float* __restrict__ tab,
                                               float* __restrict__ aout) {
    const int lane = threadIdx.x & 63;
    const int wave = threadIdx.x >> 6;
    const int bh   = blockIdx.y;
    const int h    = bh & (H_ - 1);
    const int panel = (blockIdx.x + blockIdx.y) & 31;
    const int s0 = panel * 64;
    float* ablk = aout + (size_t)bh * S_ * S_;

    const int wm = (wave >> 1) * 32, wn = (wave & 1) * 32;
    const int row = lane & 31, koff = (lane >> 5) * 8;

    const unsigned short* qp = qb + ((size_t)bh * S_ + s0 + wm + row) * DK_ + koff;
    bf16x8 qf0 = *reinterpret_cast<const bf16x8*>(qp);
    bf16x8 qf1 = *reinterpret_cast<const bf16x8*>(qp + 16);
    bf16x8 qf2 = *reinterpret_cast<const bf16x8*>(qp + 32);
    bf16x8 qf3 = *reinterpret_cast<const bf16x8*>(qp + 48);

    const float* th = tab + h * S_;
    const int ntt = panel + 1;

    const int zr = threadIdx.x >> 2;
    const int zq = threadIdx.x & 3;

    for (int tt = 0; tt < 32; ++tt) {
        const int t0 = tt * 64;
        if (tt < ntt) {
            const unsigned short* kp = kb + ((size_t)bh * S_ + t0 + wn + row) * DK_ + koff;
            f32x16 acc = {};
            acc = __builtin_amdgcn_mfma_f32_32x32x16_bf16(qf0, *reinterpret_cast<const bf16x8*>(kp),      acc, 0, 0, 0);
            acc = __builtin_amdgcn_mfma_f32_32x32x16_bf16(qf1, *reinterpret_cast<const bf16x8*>(kp + 16), acc, 0, 0, 0);
            acc = __builtin_amdgcn_mfma_f32_32x32x16_bf16(qf2, *reinterpret_cast<const bf16x8*>(kp + 32), acc, 0, 0, 0);
            acc = __builtin_amdgcn_mfma_f32_32x32x16_bf16(qf3, *reinterpret_cast<const bf16x8*>(kp + 48), acc, 0, 0, 0);
#pragma unroll
            for (int r = 0; r < 16; ++r) {
                int rowD = (r & 3) + 8 * (r >> 2) + 4 * (lane >> 5);
                int s = s0 + wm + rowD;
                int t = t0 + wn + (lane & 31);
                int d = s - t;
                float v = (d >= 0) ? acc[r] * th[d] : 0.0f;
                __builtin_nontemporal_store(v, &ablk[(size_t)s * S_ + t]);
            }
        } else {
            f32x4 z = {0.f, 0.f, 0.f, 0.f};
            float* rp = ablk + (size_t)(s0 + zr) * S_ + t0;
#pragma unroll
            for (int i = 0; i < 4; ++i)
                __builtin_nontemporal_store(z, reinterpret_cast<f32x4*>(rp) + zq + i * 4);
        }
    }
}

extern "C" void kernel_launch(void* const* d_in, const int* in_sizes, int n_in,
                              void* d_out, int out_size, void* d_ws, size_t ws_size,
                              hipStream_t stream) {
    const float* x  = (const float*)d_in[0];
    const float* wq = (const float*)d_in[1];
    const float* wk = (const float*)d_in[2];

    char* ws = (char*)d_ws;
    unsigned short* xb  = (unsigned short*)(ws);               //  8,388,608 B
    unsigned short* wqT = (unsigned short*)(ws + 8388608);     //    524,288 B
    unsigned short* wkT = (unsigned short*)(ws + 8912896);     //    524,288 B
    unsigned short* qb  = (unsigned short*)(ws + 9437184);     //  8,388,608 B
    unsigned short* kb  = (unsigned short*)(ws + 17825792);    //  8,388,608 B
    float*          tab = (float*)(ws + 26214400);             //     65,536 B

    float* out0 = (float*)d_out;
    float* aout = (float*)d_out + (size_t)B_ * S_ * D_;

    hipLaunchKernelGGL(k_convert_x, dim3((B_*S_*D_/4 + 255)/256), dim3(256), 0, stream,
                       x, xb, B_*S_*D_/4);
    hipLaunchKernelGGL(k_transpose_w, dim3((2*H_*DK_*D_ + 255)/256), dim3(256), 0, stream,
                       wq, wk, wqT, wkT);
    hipLaunchKernelGGL(k_decay, dim3((H_*S_ + 255)/256), dim3(256), 0, stream, tab);
    hipLaunchKernelGGL(k_zero, dim3((B_*S_*D_/4 + 255)/256), dim3(256), 0, stream,
                       (float4*)out0, B_*S_*D_/4);
    hipLaunchKernelGGL(k_proj, dim3(H_, (B_*S_)/128, 2), dim3(256), 0, stream,
                       xb, wqT, wkT, qb, kb);
    // MEASUREMENT: k_score launched TWICE (idempotent — same inputs, same output).
    // t_score = T_round5 - T_round4; t_others = T_round4 - t_score.
    hipLaunchKernelGGL(k_score, dim3(S_/64, B_*H_), dim3(256), 0, stream,
                       qb, kb, tab, aout);
    hipLaunchKernelGGL(k_score, dim3(S_/64, B_*H_), dim3(256), 0, stream,
                       qb, kb, tab, aout);
}

// Round 6
// 201.936 us; speedup vs baseline: 1.9551x; 1.9551x over previous
//
#include <hip/hip_runtime.h>
#include <hip/hip_bf16.h>
#include <math.h>

#define B_ 4
#define S_ 2048
#define D_ 512
#define H_ 8
#define DK_ 64

typedef __bf16 bf16x8 __attribute__((ext_vector_type(8)));
typedef float f32x16 __attribute__((ext_vector_type(16)));
typedef float f32x4 __attribute__((ext_vector_type(4)));

static __device__ __forceinline__ unsigned short f2bf(float f) {
    unsigned int u = __builtin_bit_cast(unsigned int, f);
    unsigned int r = (u + 0x7FFFu + ((u >> 16) & 1u)) >> 16;
    return (unsigned short)r;
}

// ---- x (f32) -> bf16, vectorized ----
__global__ void k_convert_x(const float* __restrict__ x, unsigned short* __restrict__ xb, int n4) {
    int i = blockIdx.x * blockDim.x + threadIdx.x;
    if (i >= n4) return;
    const float4 v = reinterpret_cast<const float4*>(x)[i];
    ushort4 o;
    o.x = f2bf(v.x); o.y = f2bf(v.y); o.z = f2bf(v.z); o.w = f2bf(v.w);
    reinterpret_cast<ushort4*>(xb)[i] = o;
}

// ---- W_Q/W_K [H][D][DK] f32 -> [H][DK][D] bf16 ----
__global__ void k_transpose_w(const float* __restrict__ wq, const float* __restrict__ wk,
                              unsigned short* __restrict__ wqT, unsigned short* __restrict__ wkT) {
    int idx = blockIdx.x * blockDim.x + threadIdx.x;
    const int n = H_ * DK_ * D_;
    const float* src = idx < n ? wq : wk;
    unsigned short* dst = idx < n ? wqT : wkT;
    int o = idx < n ? idx : idx - n;
    int d  = o % D_;
    int hk = o / D_;
    int k  = hk % DK_;
    int h  = hk / DK_;
    dst[o] = f2bf(src[(h * D_ + d) * DK_ + k]);
}

// ---- decay table tab[h][n] = gamma_h^n ----
__global__ void k_decay(float* __restrict__ tab) {
    int i = blockIdx.x * blockDim.x + threadIdx.x;
    if (i >= H_ * S_) return;
    int h = i / S_;
    int n = i % S_;
    double xv = -3.4657359027997265 - (double)h * (2.772588722239781 / 7.0);
    double g = 1.0 - exp(xv);
    tab[i] = (float)pow(g, (double)n);
}

// ---- zero output 0 (reference out == 0 exactly: GroupNorm group-size 1) ----
__global__ void k_zero(float4* __restrict__ p, int n4) {
    int i = blockIdx.x * blockDim.x + threadIdx.x;
    if (i < n4) { float4 z = {0.f, 0.f, 0.f, 0.f}; p[i] = z; }
}

// ---- projection GEMM, fused all heads: [B*S, 512] x [512, 1024(Q||K)] ----
// grid (256 m-blocks, 2 col-halves), block 256 = 4 waves.
// Block: 32 rows x 512 cols; wave: 32 rows x 128 cols (4 x f32x16 acc).
// Inner loop: 1 A-load + 4 B-loads : 4 MFMAs (vs old 3:2). x read ~2x total.
__global__ __launch_bounds__(256) void k_proj(const unsigned short* __restrict__ xb,
                                              const unsigned short* __restrict__ wqT,
                                              const unsigned short* __restrict__ wkT,
                                              unsigned short* __restrict__ qb,
                                              unsigned short* __restrict__ kb) {
    const int lane = threadIdx.x & 63;
    const int wave = threadIdx.x >> 6;
    const int m0 = blockIdx.x * 32;
    const int ncol0 = blockIdx.y * 512 + wave * 128;   // first col of this wave (0..1023)
    const int row  = lane & 31;
    const int koff = (lane >> 5) * 8;

    const unsigned short* wt = (ncol0 >> 9) ? wkT : wqT;
    unsigned short* outp     = (ncol0 >> 9) ? kb  : qb;

    const unsigned short* aptr = xb + (size_t)(m0 + row) * D_ + koff;
    const unsigned short* bptr0 = wt + (size_t)((ncol0 +  0 + row) & 511) * D_ + koff;
    const unsigned short* bptr1 = wt + (size_t)((ncol0 + 32 + row) & 511) * D_ + koff;
    const unsigned short* bptr2 = wt + (size_t)((ncol0 + 64 + row) & 511) * D_ + koff;
    const unsigned short* bptr3 = wt + (size_t)((ncol0 + 96 + row) & 511) * D_ + koff;

    f32x16 acc0 = {}, acc1 = {}, acc2 = {}, acc3 = {};
    for (int kk = 0; kk < D_; kk += 16) {
        bf16x8 a = *reinterpret_cast<const bf16x8*>(aptr + kk);
        acc0 = __builtin_amdgcn_mfma_f32_32x32x16_bf16(a, *reinterpret_cast<const bf16x8*>(bptr0 + kk), acc0, 0, 0, 0);
        acc1 = __builtin_amdgcn_mfma_f32_32x32x16_bf16(a, *reinterpret_cast<const bf16x8*>(bptr1 + kk), acc1, 0, 0, 0);
        acc2 = __builtin_amdgcn_mfma_f32_32x32x16_bf16(a, *reinterpret_cast<const bf16x8*>(bptr2 + kk), acc2, 0, 0, 0);
        acc3 = __builtin_amdgcn_mfma_f32_32x32x16_bf16(a, *reinterpret_cast<const bf16x8*>(bptr3 + kk), acc3, 0, 0, 0);
    }

    const f32x16* accs[4] = { &acc0, &acc1, &acc2, &acc3 };
#pragma unroll
    for (int nb = 0; nb < 4; ++nb) {
        int n = ncol0 + nb * 32 + (lane & 31);         // global output col
        int h = (n >> 6) & 7;
        int k = n & 63;
#pragma unroll
        for (int r = 0; r < 16; ++r) {
            int rowD = (r & 3) + 8 * (r >> 2) + 4 * (lane >> 5);
            int m = m0 + rowD;
            int bidx = m >> 11, s = m & 2047;
            outp[(((size_t)bidx * H_ + h) * S_ + s) * DK_ + k] = f2bf((*accs[nb])[r]);
        }
    }
}

// ---- scores, balanced panel streaming ----
// grid (32 panels, 32 bh), block 256 = 4 waves (2x2 of 32x32).
// sigma-permuted panel: each CU's 4 blocks {a,a+8,a+16,a+24} map to panels
// summing to a constant -> uniform per-CU work under round-robin dispatch.
// Full tiles: decay factored as th[dbase+wm-wn] * th[rowD] * (1/th[col]) ->
// 2 v_mul + 1 store per element, no gathers, no mask. Diagonal: masked gather.
__global__ __launch_bounds__(256) void k_score(const unsigned short* __restrict__ qb,
                                               const unsigned short* __restrict__ kb,
                                               const float* __restrict__ tab,
                                               float* __restrict__ aout) {
    const int lane = threadIdx.x & 63;
    const int wave = threadIdx.x >> 6;
    const int bh   = blockIdx.y;
    const int h    = bh & (H_ - 1);
    const int a    = (blockIdx.x + blockIdx.y) & 31;
    const int q = a >> 3, rr = a & 7;
    const int panel = (q == 0) ? rr : (q == 1) ? (15 - rr) : (q == 2) ? (16 + rr) : (31 - rr);
    const int s0 = panel * 64;
    float* ablk = aout + (size_t)bh * S_ * S_;

    const int wm = (wave >> 1) * 32, wn = (wave & 1) * 32;
    const int wmn = wm - wn;
    const int row = lane & 31, koff = (lane >> 5) * 8;
    const int col = lane & 31;
    const int hi  = lane >> 5;

    // Q fragments: registers for the whole kernel
    const unsigned short* qp = qb + ((size_t)bh * S_ + s0 + wm + row) * DK_ + koff;
    bf16x8 qf0 = *reinterpret_cast<const bf16x8*>(qp);
    bf16x8 qf1 = *reinterpret_cast<const bf16x8*>(qp + 16);
    bf16x8 qf2 = *reinterpret_cast<const bf16x8*>(qp + 32);
    bf16x8 qf3 = *reinterpret_cast<const bf16x8*>(qp + 48);

    const float* th = tab + h * S_;

    // hoisted per-lane decay factors
    float c1 = 1.0f / th[col];                  // gamma^(-col)
    float grc[16];
#pragma unroll
    for (int r = 0; r < 16; ++r) {
        int rowD = (r & 3) + 8 * (r >> 2) + 4 * hi;
        grc[r] = th[rowD] * c1;                 // gamma^(rowD - col)
    }

    const int zr = threadIdx.x >> 2;
    const int zq = threadIdx.x & 3;

    for (int tt = 0; tt < 32; ++tt) {
        const int t0 = tt * 64;
        if (tt <= panel) {
            const unsigned short* kp = kb + ((size_t)bh * S_ + t0 + wn + row) * DK_ + koff;
            f32x16 acc = {};
            acc = __builtin_amdgcn_mfma_f32_32x32x16_bf16(qf0, *reinterpret_cast<const bf16x8*>(kp),      acc, 0, 0, 0);
            acc = __builtin_amdgcn_mfma_f32_32x32x16_bf16(qf1, *reinterpret_cast<const bf16x8*>(kp + 16), acc, 0, 0, 0);
            acc = __builtin_amdgcn_mfma_f32_32x32x16_bf16(qf2, *reinterpret_cast<const bf16x8*>(kp + 32), acc, 0, 0, 0);
            acc = __builtin_amdgcn_mfma_f32_32x32x16_bf16(qf3, *reinterpret_cast<const bf16x8*>(kp + 48), acc, 0, 0, 0);
            if (tt < panel) {
                // full tile: d = (s0-t0) + wm-wn + rowD - col >= 1 always
                float sc = th[(panel - tt) * 64 + wmn];
#pragma unroll
                for (int r = 0; r < 16; ++r) {
                    int rowD = (r & 3) + 8 * (r >> 2) + 4 * hi;
                    int s = s0 + wm + rowD;
                    int t = t0 + wn + col;
                    ablk[(size_t)s * S_ + t] = acc[r] * grc[r] * sc;
                }
            } else {
                // diagonal tile: masked gather path
#pragma unroll
                for (int r = 0; r < 16; ++r) {
                    int rowD = (r & 3) + 8 * (r >> 2) + 4 * hi;
                    int s = s0 + wm + rowD;
                    int t = t0 + wn + col;
                    int d = s - t;
                    float v = (d >= 0) ? acc[r] * th[d] : 0.0f;
                    ablk[(size_t)s * S_ + t] = v;
                }
            }
        } else {
            f32x4 z = {0.f, 0.f, 0.f, 0.f};
            float* rp = ablk + (size_t)(s0 + zr) * S_ + t0;
#pragma unroll
            for (int i = 0; i < 4; ++i)
                reinterpret_cast<f32x4*>(rp)[zq + i * 4] = z;
        }
    }
}

extern "C" void kernel_launch(void* const* d_in, const int* in_sizes, int n_in,
                              void* d_out, int out_size, void* d_ws, size_t ws_size,
                              hipStream_t stream) {
    const float* x  = (const float*)d_in[0];
    const float* wq = (const float*)d_in[1];
    const float* wk = (const float*)d_in[2];

    char* ws = (char*)d_ws;
    unsigned short* xb  = (unsigned short*)(ws);               //  8,388,608 B
    unsigned short* wqT = (unsigned short*)(ws + 8388608);     //    524,288 B
    unsigned short* wkT = (unsigned short*)(ws + 8912896);     //    524,288 B
    unsigned short* qb  = (unsigned short*)(ws + 9437184);     //  8,388,608 B
    unsigned short* kb  = (unsigned short*)(ws + 17825792);    //  8,388,608 B
    float*          tab = (float*)(ws + 26214400);             //     65,536 B

    float* out0 = (float*)d_out;
    float* aout = (float*)d_out + (size_t)B_ * S_ * D_;

    hipLaunchKernelGGL(k_convert_x, dim3((B_*S_*D_/4 + 255)/256), dim3(256), 0, stream,
                       x, xb, B_*S_*D_/4);
    hipLaunchKernelGGL(k_transpose_w, dim3((2*H_*DK_*D_ + 255)/256), dim3(256), 0, stream,
                       wq, wk, wqT, wkT);
    hipLaunchKernelGGL(k_decay, dim3((H_*S_ + 255)/256), dim3(256), 0, stream, tab);
    hipLaunchKernelGGL(k_zero, dim3((B_*S_*D_/4 + 255)/256), dim3(256), 0, stream,
                       (float4*)out0, B_*S_*D_/4);
    hipLaunchKernelGGL(k_proj, dim3(B_*S_/32, 2), dim3(256), 0, stream,
                       xb, wqT, wkT, qb, kb);
    hipLaunchKernelGGL(k_score, dim3(S_/64, B_*H_), dim3(256), 0, stream,
                       qb, kb, tab, aout);
}